// Round 6
// baseline (8203.023 us; speedup 1.0000x reference)
//
#include <hip/hip_runtime.h>
#include <hip/hip_bf16.h>

// LSTM decoder: B=256, H=1024, L=2, T=128.
// R6: layer-cohort persistent kernel, weights resident in VGPRs.
// 256 blocks = 2 layer-cohorts x 64 j-chunks x 2 batch-halves; block =
// 64 gate-rows x 128 batch; 4 waves K-split-512, each holding its A-slice
// in 256 VGPRs (loaded once from fragment-packed weights). B direct
// global->VGPR, 3-deep prefetch, two 64-col passes. Stamp-array gates
// (ballot poll) with x-gate hidden under the safe h-half K-tiles.

typedef _Float16 half8 __attribute__((ext_vector_type(8)));
typedef _Float16 half4 __attribute__((ext_vector_type(4)));
typedef float f32x4 __attribute__((ext_vector_type(4)));

#define HSZ 1024
#define BSZ 256
#define TSZ 128

// ---------------- prep: vraw = W^T u (two-stage deterministic) ----------------
__global__ __launch_bounds__(256) void prep_vraw1(
    const float* __restrict__ Wih, const float* __restrict__ Whh,
    const float* __restrict__ uih, const float* __restrict__ uhh,
    float* __restrict__ vpart) {
  int bx = blockIdx.x;                 // 256 blocks: m(4) x rc(16) x jc(4)
  int m = bx >> 6, rc = (bx >> 2) & 15, jc = bx & 3;
  int j = jc * 256 + threadIdx.x;
  const float* W = (m < 2 ? Wih : Whh) + ((size_t)(m & 1) << 22);
  const float* u = (m < 2 ? uih : uhh) + (m & 1) * 4096;
  float acc = 0.f;
  int rbase = rc * 256;
  for (int r = 0; r < 256; ++r)
    acc += W[(size_t)(rbase + r) * 1024 + j] * u[rbase + r];
  vpart[(m * 16 + rc) * 1024 + j] = acc;
}

__global__ __launch_bounds__(256) void prep_vraw2(
    const float* __restrict__ vpart, float* __restrict__ vraw) {
  int i = blockIdx.x * 256 + threadIdx.x;   // 0..4095 -> m*1024+j
  int m = i >> 10;
  float acc = 0.f;
  for (int rc = 0; rc < 16; ++rc)
    acc += vpart[(m * 16 + rc) * 1024 + (i & 1023)];
  vraw[i] = acc;
}

// ---------------- prep: wv = W @ vraw ----------------
__global__ __launch_bounds__(256) void prep_wv(
    const float* __restrict__ Wih, const float* __restrict__ Whh,
    const float* __restrict__ vraw, float* __restrict__ wv) {
  int m = blockIdx.y;
  int w = threadIdx.x >> 6, l = threadIdx.x & 63;
  int r = blockIdx.x * 4 + w;
  const float* W = (m < 2 ? Wih : Whh) + ((size_t)(m & 1) << 22) + (size_t)r * 1024;
  const float* v = vraw + m * 1024;
  float acc = 0.f;
  for (int it = 0; it < 4; ++it) {
    int j = it * 256 + l * 4;
    float4 w4 = *(const float4*)(W + j);
    float4 v4 = *(const float4*)(v + j);
    acc += w4.x * v4.x + w4.y * v4.y + w4.z * v4.z + w4.w * v4.w;
  }
  for (int o = 32; o; o >>= 1) acc += __shfl_down(acc, o);
  if (l == 0) wv[m * 4096 + r] = acc;
}

// ---------------- prep: inv_sigma = ||vraw|| / ||wv|| ----------------
__global__ __launch_bounds__(256) void prep_sig(
    const float* __restrict__ vraw, const float* __restrict__ wv,
    float* __restrict__ invsig) {
  int m = blockIdx.x, tid = threadIdx.x;
  __shared__ float red[256];
  float sv = 0.f, sw = 0.f;
  for (int i = tid; i < 1024; i += 256) { float x = vraw[m * 1024 + i]; sv += x * x; }
  for (int i = tid; i < 4096; i += 256) { float x = wv[m * 4096 + i]; sw += x * x; }
  red[tid] = sv; __syncthreads();
  for (int s = 128; s; s >>= 1) { if (tid < s) red[tid] += red[tid + s]; __syncthreads(); }
  float svt = red[0]; __syncthreads();
  red[tid] = sw; __syncthreads();
  for (int s = 128; s; s >>= 1) { if (tid < s) red[tid] += red[tid + s]; __syncthreads(); }
  if (tid == 0) invsig[m] = sqrtf(svt / red[0]);
}

// ---------------- prep: fragment-packed A (f16, scaled) ----------------
// Layout: granule id = ((((layer*64+jc)*4 + w)*64 + (m*16+s))*64 + lane),
// 16 B each. Frag (m,s) of wave w: lane holds W[m*1024+jc*16+(lane&15)]
// [k0(s) + (lane>>4)*8 .. +8], k0 = s<8 ? 1024+w*256+s*32 : w*256+(s-8)*32.
__global__ __launch_bounds__(256) void prep_apack(
    const float* __restrict__ Wih, const float* __restrict__ Whh,
    const float* __restrict__ invsig, _Float16* __restrict__ apack) {
  unsigned id = blockIdx.x * 256 + threadIdx.x;   // 0 .. 2^21-1
  int lane = id & 63, f = (id >> 6) & 63, w = (id >> 12) & 3;
  int jc = (id >> 14) & 63, layer = (id >> 20) & 1;
  int m = f >> 4, s = f & 15;
  int lr = lane & 15, lk = lane >> 4;
  int row = m * 1024 + jc * 16 + lr;
  int k = (s < 8) ? (1024 + w * 256 + s * 32 + lk * 8)
                  : (w * 256 + (s - 8) * 32 + lk * 8);
  const float* src; float sc;
  if (k < 1024) {
    src = Wih + ((size_t)layer << 22) + (size_t)row * 1024 + k;
    sc = invsig[layer];
  } else {
    src = Whh + ((size_t)layer << 22) + (size_t)row * 1024 + (k - 1024);
    sc = invsig[2 + layer];
  }
  float4 v0 = *(const float4*)src;
  float4 v1 = *(const float4*)(src + 4);
  half8 o = { (_Float16)(v0.x * sc), (_Float16)(v0.y * sc),
              (_Float16)(v0.z * sc), (_Float16)(v0.w * sc),
              (_Float16)(v1.x * sc), (_Float16)(v1.y * sc),
              (_Float16)(v1.z * sc), (_Float16)(v1.w * sc) };
  *(half8*)(apack + (size_t)id * 8) = o;
}

__global__ __launch_bounds__(256) void prep_bias(
    const float* __restrict__ b_ih, const float* __restrict__ b_hh,
    float* __restrict__ bias) {
  int i = blockIdx.x * 256 + threadIdx.x;
  if (i < 8192) bias[i] = b_ih[i] + b_hh[i];
}

__global__ __launch_bounds__(256) void prep_init(
    const float* __restrict__ x0, const float* __restrict__ h0,
    const float* __restrict__ c0, _Float16* __restrict__ Xinit,
    _Float16* __restrict__ H0p0, _Float16* __restrict__ H1p0,
    float* __restrict__ C0, float* __restrict__ C1) {
  int i = blockIdx.x * 256 + threadIdx.x;   // 0..262143
  Xinit[i] = (_Float16)x0[i];
  H0p0[i]  = (_Float16)h0[i];
  H1p0[i]  = (_Float16)h0[262144 + i];
  C0[i] = c0[i];
  C1[i] = c0[262144 + i];
}

// ---------------- gates: stamp arrays + wave ballot poll ----------------
static __device__ __forceinline__ void wait_ge(const unsigned* a, int lane, int tgt) {
  unsigned v = __hip_atomic_load(a + lane, __ATOMIC_RELAXED, __HIP_MEMORY_SCOPE_AGENT);
  while (__any(v < (unsigned)tgt)) {
    __builtin_amdgcn_s_sleep(2);
    v = __hip_atomic_load(a + lane, __ATOMIC_RELAXED, __HIP_MEMORY_SCOPE_AGENT);
  }
  __builtin_amdgcn_fence(__ATOMIC_ACQUIRE, "agent");   // inv L1/stale L2
}

// ---------------- the persistent cohort kernel ----------------
__global__ __launch_bounds__(256, 1) void lstm_cohort(
    const _Float16* __restrict__ Apack, const float* __restrict__ bias,
    const _Float16* __restrict__ Xinit,
    _Float16* __restrict__ H00, _Float16* __restrict__ H01,
    _Float16* __restrict__ H10, _Float16* __restrict__ H11,
    float* __restrict__ C0, float* __restrict__ C1,
    float* __restrict__ out, unsigned* __restrict__ arr) {
  __shared__ float part[4][64][67];   // [K-partial p][batch col][gate-row] +pad
  const int tid = threadIdx.x, lane = tid & 63, w = tid >> 6;
  const int lr = lane & 15, lk = lane >> 4;
  const int bx = blockIdx.x;
  const int layer = bx & 1, jc = (bx >> 1) & 63, bh = bx >> 7;
  const int j0 = jc * 16, bm0 = bh * 128;

  // ---- load this wave's A K-slice into registers (stays for the whole run)
  half8 a[4][16];
  {
    const _Float16* ab = Apack +
        ((size_t)(((layer * 64 + jc) * 4 + w) * 64)) * 512 + lane * 8;
#pragma unroll
    for (int m = 0; m < 4; ++m)
#pragma unroll
      for (int s = 0; s < 16; ++s)
        a[m][s] = *(const half8*)(ab + (size_t)(m * 16 + s) * 512);
  }

  float* cb = layer ? C1 : C0;
  const float* bs = bias + layer * 4096;
  unsigned* ownA = arr + (layer * 2 + bh) * 64;
  unsigned* othA = arr + ((1 - layer) * 2 + bh) * 64;

  float4 bI = *(const float4*)(bs + j0 + w * 4);
  float4 bF = *(const float4*)(bs + 1024 + j0 + w * 4);
  float4 bG = *(const float4*)(bs + 2048 + j0 + w * 4);
  float4 bO = *(const float4*)(bs + 3072 + j0 + w * 4);
  const float* bIp = (const float*)&bI; const float* bFp = (const float*)&bF;
  const float* bGp = (const float*)&bG; const float* bOp = (const float*)&bO;

#pragma unroll 1
  for (int t = 0; t < TSZ; ++t) {
    const int ph = 2 * t + layer;
    const _Float16* hb = layer ? ((t & 1) ? H11 : H10) : ((t & 1) ? H01 : H00);
    const _Float16* xb = layer ? ((t & 1) ? H00 : H01)
                               : (t == 0 ? Xinit : ((t & 1) ? H11 : H10));
    _Float16* hw = layer ? ((t & 1) ? H10 : H11) : ((t & 1) ? H00 : H01);

    // h-gate: own cohort finished step t-1 (their h writes visible)
    if (ph >= 2) wait_ge(ownA, lane, ph - 1);

#pragma unroll 1
    for (int nh = 0; nh < 2; ++nh) {
      unsigned ro[4];
#pragma unroll
      for (int n = 0; n < 4; ++n)
        ro[n] = (unsigned)(bm0 + nh * 64 + n * 16 + lr) * 1024 + lk * 8;
      const int wk = w * 256;

      f32x4 acc[4][4];
#pragma unroll
      for (int m = 0; m < 4; ++m)
#pragma unroll
        for (int n = 0; n < 4; ++n) acc[m][n] = (f32x4){0.f, 0.f, 0.f, 0.f};

      half8 bb[3][4];
      // tiles 0..7 = h-part (safe pre-x-gate), 8..15 = x-part
#define LOADT(BUF, T) do {                                                    \
      const _Float16* sp = ((T) < 8) ? hb : xb;                               \
      const int c0 = wk + ((T) & 7) * 32;                                     \
      _Pragma("unroll")                                                       \
      for (int n = 0; n < 4; ++n)                                             \
        bb[BUF][n] = *(const half8*)(sp + ro[n] + c0);                        \
    } while (0)

      LOADT(0, 0); LOADT(1, 1); LOADT(2, 2);
#pragma unroll
      for (int T = 0; T < 16; ++T) {
#pragma unroll
        for (int m = 0; m < 4; ++m)
#pragma unroll
          for (int n = 0; n < 4; ++n)
            acc[m][n] = __builtin_amdgcn_mfma_f32_16x16x32_f16(
                a[m][T], bb[T % 3][n], acc[m][n], 0, 0, 0);
        // x-gate once per phase, right before the first x-tile load issues
        if (T == 5 && nh == 0 && ph >= 1) wait_ge(othA, lane, ph);
        if (T + 3 < 16) LOADT(T % 3, T + 3);
      }
#undef LOADT

      // ---- K-partial reduce through LDS + fused LSTM epilogue
      __syncthreads();   // prior pass/phase reads of part[] done
#pragma unroll
      for (int m = 0; m < 4; ++m)
#pragma unroll
        for (int n = 0; n < 4; ++n)
#pragma unroll
          for (int j = 0; j < 4; ++j)
            part[w][n * 16 + lr][m * 16 + lk * 4 + j] = acc[m][n][j];
      __syncthreads();

      {
        const size_t idx = (size_t)(bm0 + nh * 64 + lane) * 1024 + j0 + w * 4;
        float4 c4 = *(const float4*)(cb + idx);
        const float* cp = (const float*)&c4;
        float cn[4], hn[4];
#pragma unroll
        for (int jj = 0; jj < 4; ++jj) {
          const int r = w * 4 + jj;
          float gi = part[0][lane][r] + part[1][lane][r] +
                     part[2][lane][r] + part[3][lane][r] + bIp[jj];
          float gf = part[0][lane][16 + r] + part[1][lane][16 + r] +
                     part[2][lane][16 + r] + part[3][lane][16 + r] + bFp[jj];
          float gg = part[0][lane][32 + r] + part[1][lane][32 + r] +
                     part[2][lane][32 + r] + part[3][lane][32 + r] + bGp[jj];
          float go = part[0][lane][48 + r] + part[1][lane][48 + r] +
                     part[2][lane][48 + r] + part[3][lane][48 + r] + bOp[jj];
          float si = 1.f / (1.f + __expf(-gi));
          float sf = 1.f / (1.f + __expf(-gf));
          float so = 1.f / (1.f + __expf(-go));
          float e2g = __expf(fminf(fmaxf(2.f * gg, -30.f), 30.f));
          float tg = (e2g - 1.f) / (e2g + 1.f);
          float cv = sf * cp[jj] + si * tg;
          float e2c = __expf(fminf(fmaxf(2.f * cv, -30.f), 30.f));
          float tc = (e2c - 1.f) / (e2c + 1.f);
          cn[jj] = cv;
          hn[jj] = so * tc;
        }
        float4 cno = { cn[0], cn[1], cn[2], cn[3] };
        *(float4*)(cb + idx) = cno;
        half4 h4 = { (_Float16)hn[0], (_Float16)hn[1],
                     (_Float16)hn[2], (_Float16)hn[3] };
        *(half4*)(hw + idx) = h4;
        if (layer) {
          float4 y4 = { hn[0], hn[1], hn[2], hn[3] };
          *(float4*)(out + ((size_t)(bm0 + nh * 64 + lane) * TSZ + t) * HSZ +
                     j0 + w * 4) = y4;
        }
      }
    }  // nh

    // publish this block's step: drain all waves' stores, then release stamp
    __syncthreads();
    if (tid == 0)
      __hip_atomic_store(ownA + jc, (unsigned)(ph + 1),
                         __ATOMIC_RELEASE, __HIP_MEMORY_SCOPE_AGENT);
  }  // t
}

extern "C" void kernel_launch(void* const* d_in, const int* in_sizes, int n_in,
                              void* d_out, int out_size, void* d_ws, size_t ws_size,
                              hipStream_t stream) {
  (void)in_sizes; (void)n_in; (void)out_size; (void)ws_size;
  const float* x0   = (const float*)d_in[0];
  const float* h0   = (const float*)d_in[1];
  const float* c0   = (const float*)d_in[2];
  const float* Wih  = (const float*)d_in[3];
  const float* Whh  = (const float*)d_in[4];
  const float* b_ih = (const float*)d_in[5];
  const float* b_hh = (const float*)d_in[6];
  const float* u_ih = (const float*)d_in[7];
  const float* u_hh = (const float*)d_in[8];
  float* out = (float*)d_out;

  char* ws = (char*)d_ws;
  size_t off = 0;
  auto alloc = [&](size_t bytes) -> void* {
    void* p = ws + off;
    off = (off + bytes + 255) & ~(size_t)255;
    return p;
  };
  _Float16* apack  = (_Float16*)alloc((size_t)2 * 4096 * 2048 * 2);
  float*    vpart  = (float*)alloc((size_t)4 * 16 * 1024 * 4);
  float*    vraw   = (float*)alloc((size_t)4 * 1024 * 4);
  float*    wv     = (float*)alloc((size_t)4 * 4096 * 4);
  float*    invsig = (float*)alloc(16);
  float*    bias   = (float*)alloc((size_t)2 * 4096 * 4);
  _Float16* Xinit  = (_Float16*)alloc((size_t)262144 * 2);
  _Float16* Hb[2][2];
  for (int a = 0; a < 2; ++a)
    for (int p = 0; p < 2; ++p)
      Hb[a][p] = (_Float16*)alloc((size_t)262144 * 2);
  float* Cb[2];
  Cb[0] = (float*)alloc((size_t)262144 * 4);
  Cb[1] = (float*)alloc((size_t)262144 * 4);
  unsigned* arr = (unsigned*)alloc(4 * 64 * sizeof(unsigned));

  prep_vraw1<<<256, 256, 0, stream>>>(Wih, Whh, u_ih, u_hh, vpart);
  prep_vraw2<<<16, 256, 0, stream>>>(vpart, vraw);
  prep_wv<<<dim3(1024, 4), 256, 0, stream>>>(Wih, Whh, vraw, wv);
  prep_sig<<<4, 256, 0, stream>>>(vraw, wv, invsig);
  prep_apack<<<8192, 256, 0, stream>>>(Wih, Whh, invsig, apack);
  prep_bias<<<32, 256, 0, stream>>>(b_ih, b_hh, bias);
  prep_init<<<1024, 256, 0, stream>>>(x0, h0, c0, Xinit, Hb[0][0], Hb[1][0], Cb[0], Cb[1]);
  hipMemsetAsync(arr, 0, 4 * 64 * sizeof(unsigned), stream);

  lstm_cohort<<<dim3(256), dim3(256), 0, stream>>>(
      apack, bias, Xinit, Hb[0][0], Hb[0][1], Hb[1][0], Hb[1][1],
      Cb[0], Cb[1], out, arr);
}